// Round 8
// baseline (478.553 us; speedup 1.0000x reference)
//
#include <hip/hip_runtime.h>
#include <hip/hip_bf16.h>

typedef __hip_bfloat16 bf16;
typedef __attribute__((ext_vector_type(8))) short s16x8;   // 8 bf16 (4 VGPRs) MFMA frag
typedef __attribute__((ext_vector_type(4))) float f32x4;   // MFMA accumulator

#define B_ 2
#define S_ 4096
#define H_ 2048
#define R_ 2048
#define M_ 8192      // B*S
#define NB_ 16
#define BW_ 128
#define CHUNK 64     // scan chunk length
#define NCH 64       // S/CHUNK

__device__ __forceinline__ short f2b_s(float f) {
    return (short)__builtin_bit_cast(unsigned short, __float2bfloat16(f));
}
__device__ __forceinline__ float b2f_s(short s) {
    unsigned int u = ((unsigned int)(unsigned short)s) << 16;
    return __builtin_bit_cast(float, u);
}
__device__ __forceinline__ float sigm_fast(float x) { return 1.f / (1.f + __expf(-x)); }

// async global->LDS, 16B per lane; LDS dest must be wave-uniform base + lane*16
__device__ __forceinline__ void async_g2l(const void* g, void* l) {
    __builtin_amdgcn_global_load_lds((const __attribute__((address_space(1))) void*)g,
                                     (__attribute__((address_space(3))) void*)l, 16, 0, 0);
}

// ---------------- merged cast fp32 -> bf16 for x / Wxy / Wres ----------------
__global__ __launch_bounds__(256) void cast_all(const float* __restrict__ x,
                                                const float* __restrict__ wxy,
                                                const float* __restrict__ wres,
                                                bf16* __restrict__ xbf,
                                                bf16* __restrict__ wxyb,
                                                bf16* __restrict__ wresb) {
    int idx = blockIdx.x * 256 + threadIdx.x;
    const float* in; bf16* out; int off;
    if (idx < 2097152)      { in = x;    out = xbf;   off = idx; }
    else if (idx < 3145728) { in = wxy;  out = wxyb;  off = idx - 2097152; }
    else                    { in = wres; out = wresb; off = idx - 3145728; }
    size_t i8 = (size_t)off * 8;
    float4 v0 = *(const float4*)(in + i8);
    float4 v1 = *(const float4*)(in + i8 + 4);
    s16x8 o;
    o[0] = f2b_s(v0.x); o[1] = f2b_s(v0.y); o[2] = f2b_s(v0.z); o[3] = f2b_s(v0.w);
    o[4] = f2b_s(v1.x); o[5] = f2b_s(v1.y); o[6] = f2b_s(v1.z); o[7] = f2b_s(v1.w);
    *(s16x8*)(out + i8) = o;
}

// ---------------- transpose-cast gate weights via LDS tile (+ sp8 in block 32) ----
__global__ __launch_bounds__(256) void wcast_T(const float* __restrict__ igw,
                                               const float* __restrict__ agw,
                                               const float* __restrict__ apar,
                                               bf16* __restrict__ wT,
                                               float* __restrict__ sp8) {
    int blk = blockIdx.x;
    int tid = threadIdx.x;
    if (blk == 32) {
#pragma unroll
        for (int it = 0; it < 8; ++it) {
            int r = it * 256 + tid;
            float ap = apar[r];
            sp8[r] = 8.f * (ap > 20.f ? ap : log1pf(expf(ap)));
        }
        return;
    }
    __shared__ float tile[128 * 129];
    int p = blk >> 4, n = blk & 15;
    const float* w = (p ? agw : igw) + (size_t)n * 16384;   // [i][j] row-major
#pragma unroll
    for (int it = 0; it < 64; ++it) {
        int u = it * 256 + tid;           // element: i = u>>7, j = u&127
        tile[(u >> 7) * 129 + (u & 127)] = w[u];
    }
    __syncthreads();
    bf16* o = wT + (size_t)blk * 16384;
#pragma unroll
    for (int it = 0; it < 64; ++it) {
        int u = it * 256 + tid;           // output elem: j = u>>7, i = u&127
        o[u] = __float2bfloat16(tile[(u & 127) * 129 + (u >> 7)]);
    }
}

// ---------------- generic NT GEMM: C[M,N] = A[M,K] * B[N,K]^T, bf16 in, OutT out ----
// 128x128 tile, BK=64, 4 waves 2x2, 64x64/wave, 16x16x32 MFMA, XOR-swizzled LDS,
// global_load_lds width=16 staging. launch_bounds(256,4): 4 blocks/CU.
// PROVEN: ~1086 TF, MfmaUtil 52%, 0 conflicts (R0/R5/R7). GEMM structure FROZEN
// (R1-R6: three 256^2 deep-pipeline schedules all lost, 38-43% MfmaUtil).
// R8: gelu_from -- blocks with nBase >= gelu_from apply exact gelu in the epilogue
// (per-block uniform branch; moves erff out of passB, hides under MFMA shadow).
__device__ __forceinline__ void store_c(float* p, float v) { *p = v; }
__device__ __forceinline__ void store_c(bf16* p, float v) { *p = __float2bfloat16(v); }

template <typename OutT>
__global__ __launch_bounds__(256, 4) void gemm_bt(const bf16* __restrict__ A,
                                                  const bf16* __restrict__ Bm,
                                                  OutT* __restrict__ C,
                                                  int K, int lda, int ldb, int ldc,
                                                  int gelu_from) {
    __shared__ __align__(16) short As[128 * 64];
    __shared__ __align__(16) short Bs[128 * 64];
    const int tid = threadIdx.x;
    const int lane = tid & 63, wave = tid >> 6;
    const int waveM = wave >> 1, waveN = wave & 1;
    const int mBase = blockIdx.y * 128, nBase = blockIdx.x * 128;
    const int fm = lane & 15, q = lane >> 4;
    const bool dog = (nBase >= gelu_from);

    f32x4 acc[4][4];
#pragma unroll
    for (int i = 0; i < 4; ++i)
#pragma unroll
        for (int j = 0; j < 4; ++j) acc[i][j] = (f32x4){0.f, 0.f, 0.f, 0.f};

    for (int k0 = 0; k0 < K; k0 += 64) {
        __syncthreads();
#pragma unroll
        for (int it = 0; it < 4; ++it) {
            int off = it * 4096 + tid * 16;          // byte offset in tile (lane-contig)
            int r = off >> 7;                        // row
            int g = ((off & 127) >> 4) ^ (r & 7);    // source k-group for this slot
            async_g2l(A + (size_t)(mBase + r) * lda + k0 + g * 8, (char*)As + off);
            async_g2l(Bm + (size_t)(nBase + r) * ldb + k0 + g * 8, (char*)Bs + off);
        }
        __syncthreads();
#pragma unroll
        for (int s = 0; s < 2; ++s) {
            s16x8 af[4], bfr[4];
#pragma unroll
            for (int i = 0; i < 4; ++i) {
                int row = waveM * 64 + i * 16 + fm;
                af[i] = *(const s16x8*)((char*)As + row * 128 + ((((s << 2) + q) ^ (row & 7)) << 4));
                int col = waveN * 64 + i * 16 + fm;
                bfr[i] = *(const s16x8*)((char*)Bs + col * 128 + ((((s << 2) + q) ^ (col & 7)) << 4));
            }
#pragma unroll
            for (int i = 0; i < 4; ++i)
#pragma unroll
                for (int j = 0; j < 4; ++j)
                    acc[i][j] = __builtin_amdgcn_mfma_f32_16x16x32_bf16(af[i], bfr[j], acc[i][j], 0, 0, 0);
        }
    }
    // C/D layout: col=lane&15, row=q*4+reg (m89/m91-verified)
#pragma unroll
    for (int i = 0; i < 4; ++i) {
        int rowg = mBase + waveM * 64 + i * 16 + q * 4;
#pragma unroll
        for (int j = 0; j < 4; ++j) {
            int colg = nBase + waveN * 64 + j * 16 + fm;
#pragma unroll
            for (int rr = 0; rr < 4; ++rr) {
                float v = acc[i][j][rr];
                if (dog) v = 0.5f * v * (1.f + erff(v * 0.70710678f));
                store_c(C + (size_t)(rowg + rr) * ldc + colg, v);
            }
        }
    }
}

// ------- fused: causal conv + block-diag dual gate GEMM + RG-LRU + chunk scan -------
// grid (NB_, M_/64): one block = one (batch, 64-step chunk, 128-channel block).
// Emits running per-chunk state (hloc_t, cum_t): h_full = hloc + cum*carry.
// Chunk summary packed as float2 {cum, h} for scan_carry.
__global__ __launch_bounds__(256) void gate_kernel(const bf16* __restrict__ xy,
                                                   const float* __restrict__ cw,
                                                   const float* __restrict__ cb,
                                                   const bf16* __restrict__ wT,
                                                   const float* __restrict__ igb,
                                                   const float* __restrict__ agb,
                                                   const float* __restrict__ sp8,
                                                   bf16* __restrict__ hloc_out,
                                                   bf16* __restrict__ cum_out,
                                                   float2* __restrict__ AH) {
    __shared__ __align__(16) short As[64 * 128];     // 16 KB; xc tile -> nx tile -> h tile
    __shared__ __align__(16) char  Wmem[128 * 256];  // 32 KB; Xs raw -> W tile -> a/cum f32
    short* Xs   = (short*)Wmem;                      // 67 rows x 128 shorts (raw xy window)
    short* Ws   = (short*)Wmem;
    float* a_sh = (float*)Wmem;
    const int n = blockIdx.x;
    const int mBase = blockIdx.y * 64;
    const int tid = threadIdx.x;
    const int lane = tid & 63, wave = tid >> 6;
    const int fm = lane & 15, q = lane >> 4;
    const int t0 = mBase & (S_ - 1);

    // 1. stage xy window: rows rr=0..66 <-> m = mBase + rr - 3 (zero outside batch)
#pragma unroll
    for (int it = 0; it < 5; ++it) {
        int u = it * 256 + tid;              // (rr, gg): rr = u>>4, gg = u&15
        if (u < 67 * 16) {
            int rr = u >> 4, gg = u & 15;
            s16x8 v = (s16x8){0, 0, 0, 0, 0, 0, 0, 0};
            if (t0 != 0 || rr >= 3) {
                int m = mBase + rr - 3;
                v = *(const s16x8*)(xy + (size_t)m * 4096 + n * BW_ + gg * 8);
            }
            *(s16x8*)((char*)Xs + u * 16) = v;
        }
    }
    __syncthreads();

    // 2. conv into As (swizzled bf16): thread = (col, row-half), sliding 4-tap window
    {
        int col = tid & 127, rh = tid >> 7;
        int rbase = n * BW_ + col;
        float w0c = cw[rbase], w1c = cw[R_ + rbase], w2c = cw[2 * R_ + rbase],
              w3c = cw[3 * R_ + rbase];
        float bc = cb[rbase];
        int r0 = rh * 32;
        float xm3 = b2f_s(Xs[(r0 + 0) * 128 + col]);
        float xm2 = b2f_s(Xs[(r0 + 1) * 128 + col]);
        float xm1 = b2f_s(Xs[(r0 + 2) * 128 + col]);
#pragma unroll
        for (int rw = 0; rw < 32; ++rw) {
            int row = r0 + rw;
            float x0 = b2f_s(Xs[(row + 3) * 128 + col]);
            float v = bc + w0c * xm3 + w1c * xm2 + w2c * xm1 + w3c * x0;
            xm3 = xm2; xm2 = xm1; xm1 = x0;
            *(short*)((char*)As + row * 256 + ((((col >> 3)) ^ (row & 15)) << 4) +
                      (col & 7) * 2) = f2b_s(v);
        }
    }
    __syncthreads();   // As ready; Xs region dead

    // 3. stage Ws for input gate
    const bf16* w0 = wT + (size_t)n * 16384;
#pragma unroll
    for (int it = 0; it < 8; ++it) {
        int off = it * 4096 + tid * 16;
        int j = off >> 8;
        int g = ((off & 255) >> 4) ^ (j & 15);
        async_g2l(w0 + j * 128 + g * 8, (char*)Ws + off);
    }
    __syncthreads();

    f32x4 accI[8], accA[8];
#pragma unroll
    for (int jj = 0; jj < 8; ++jj) {
        accI[jj] = (f32x4){0.f, 0.f, 0.f, 0.f};
        accA[jj] = (f32x4){0.f, 0.f, 0.f, 0.f};
    }

    const int row = wave * 16 + fm;
#pragma unroll
    for (int s = 0; s < 4; ++s) {
        s16x8 af = *(const s16x8*)((char*)As + row * 256 + ((((s << 2) + q) ^ (row & 15)) << 4));
#pragma unroll
        for (int jj = 0; jj < 8; ++jj) {
            int wrow = jj * 16 + fm;
            s16x8 bw = *(const s16x8*)((char*)Ws + wrow * 256 + ((((s << 2) + q) ^ (wrow & 15)) << 4));
            accI[jj] = __builtin_amdgcn_mfma_f32_16x16x32_bf16(af, bw, accI[jj], 0, 0, 0);
        }
    }
    __syncthreads();  // all waves done reading Ws (gate 1)
    // 4. stage Ws for a gate
    const bf16* w1 = wT + (size_t)(NB_ + n) * 16384;
#pragma unroll
    for (int it = 0; it < 8; ++it) {
        int off = it * 4096 + tid * 16;
        int j = off >> 8;
        int g = ((off & 255) >> 4) ^ (j & 15);
        async_g2l(w1 + j * 128 + g * 8, (char*)Ws + off);
    }
    __syncthreads();
#pragma unroll
    for (int s = 0; s < 4; ++s) {
        s16x8 af = *(const s16x8*)((char*)As + row * 256 + ((((s << 2) + q) ^ (row & 15)) << 4));
#pragma unroll
        for (int jj = 0; jj < 8; ++jj) {
            int wrow = jj * 16 + fm;
            s16x8 bw = *(const s16x8*)((char*)Ws + wrow * 256 + ((((s << 2) + q) ^ (wrow & 15)) << 4));
            accA[jj] = __builtin_amdgcn_mfma_f32_16x16x32_bf16(af, bw, accA[jj], 0, 0, 0);
        }
    }
    __syncthreads();  // MFMA reads of As/Ws done; epilogue may overwrite both

    // 5. epilogue: C/D col=fm, row=q*4+rr. a into a_sh; nx into own As slot.
#pragma unroll
    for (int jj = 0; jj < 8; ++jj) {
        int col = jj * 16 + fm;
        int r = n * BW_ + col;
        float bi = igb[r], ba = agb[r];
        float s8 = sp8[r];
#pragma unroll
        for (int rr = 0; rr < 4; ++rr) {
            int rowl = wave * 16 + q * 4 + rr;
            short* slot = (short*)((char*)As + rowl * 256 +
                          ((((col >> 3)) ^ (rowl & 15)) << 4) + (col & 7) * 2);
            float xcv = b2f_s(*slot);
            float xg = accI[jj][rr] + bi;
            float ag = accA[jj][rr] + ba;
            float la = -s8 * sigm_fast(ag);
            float av = __expf(la);
            float t2 = 2.f * la;
            float nem = (t2 > -0.125f)
                ? -t2 * (1.f + t2 * (0.5f + t2 * (0.16666667f + t2 * 0.04166667f)))
                : 1.f - av * av;
            float nxv = xcv * sigm_fast(xg) * sqrtf(nem);
            short nxs = f2b_s(nxv);
            a_sh[rowl * 128 + col] = av;
            *slot = nxs;                       // same slot this thread read; no race
        }
    }
    __syncthreads();

    // 6. chunk scan (threads 0..127, serial over t): consume a (a_sh) and nx (As),
    //    leave h (bf16) in the As slot and cum (f32) in the a_sh slot (same-thread WAR).
    if (tid < 128) {
        int col = tid;
        float h = 0.f, cum = 1.f;
#pragma unroll 4
        for (int t = 0; t < CHUNK; ++t) {
            short* slot = (short*)((char*)As + t * 256 +
                          ((((col >> 3)) ^ (t & 15)) << 4) + (col & 7) * 2);
            float a = a_sh[t * 128 + col];
            float nxv = b2f_s(*slot);
            h = fmaf(a, h, nxv);
            cum *= a;
            *slot = f2b_s(h);
            a_sh[t * 128 + col] = cum;
        }
        int b = mBase >> 12, c = (mBase & (S_ - 1)) >> 6;
        int so = ((b * NCH + c) << 11) + n * BW_ + col;
        AH[so] = make_float2(cum, h);
    }
    __syncthreads();

    // 7. coalesced emit: unit u = (t, gg): 8 cols gg*8..+7. h granule is one s16x8
    //    (cols of a gg share a 16B granule, order col&7); cum packed from a_sh f32.
#pragma unroll
    for (int it = 0; it < 4; ++it) {
        int u = it * 256 + tid;
        int t = u >> 4, gg = u & 15;
        s16x8 hv = *(const s16x8*)((char*)As + t * 256 + ((gg ^ (t & 15)) << 4));
        s16x8 cv;
#pragma unroll
        for (int i = 0; i < 8; ++i) cv[i] = f2b_s(a_sh[t * 128 + gg * 8 + i]);
        size_t o = (size_t)(mBase + t) * R_ + n * BW_ + gg * 8;
        *(s16x8*)(hloc_out + o) = hv;
        *(s16x8*)(cum_out + o) = cv;
    }
}

// carry into each chunk: 4096 independent 64-step scans; float2-packed summaries,
// batch-8 static-indexed prefetch so the 16 loads issue ahead of the fma chain.
__global__ __launch_bounds__(256) void scan_carry(const float2* __restrict__ AH,
                                                  float* __restrict__ carry) {
    int idx = blockIdx.x * 256 + threadIdx.x;  // B*R = 4096
    int r = idx & (R_ - 1), b = idx >> 11;
    int base = b * NCH * R_ + r;
    float cy = 0.f;
    for (int c0 = 0; c0 < NCH; c0 += 8) {
        float2 v[8];
#pragma unroll
        for (int j = 0; j < 8; ++j) v[j] = AH[base + (c0 + j) * R_];
#pragma unroll
        for (int j = 0; j < 8; ++j) {
            carry[base + (c0 + j) * R_] = cy;
            cy = fmaf(v[j].x, cy, v[j].y);
        }
    }
}

// passB (elementwise): h_full = hloc + cum*carry; g = ygelu * h_full -> bf16.
// y columns of xy already hold gelu(y) (applied in GEMM1 epilogue) -> no erf here.
__global__ __launch_bounds__(256) void scan_passB(const bf16* __restrict__ hloc,
                                                  const bf16* __restrict__ cum,
                                                  const float* __restrict__ carry,
                                                  const bf16* __restrict__ xy,
                                                  bf16* __restrict__ g_out) {
    int idx = blockIdx.x * 256 + threadIdx.x;   // M*R/8 = 2097152 units
    int m = idx >> 8;                           // row
    int r = (idx & 255) << 3;                   // col*8
    int b = m >> 12, c = (m & 4095) >> 6;
    int so = ((b * NCH + c) << 11) + r;
    size_t o = (size_t)m * R_ + r;
    s16x8 hv = *(const s16x8*)(hloc + o);
    s16x8 cv = *(const s16x8*)(cum + o);
    float4 cy0 = *(const float4*)(carry + so);
    float4 cy1 = *(const float4*)(carry + so + 4);
    s16x8 yv = *(const s16x8*)(xy + (size_t)m * 4096 + 2048 + r);
    float cya0 = cy0.x, cya1 = cy0.y, cya2 = cy0.z, cya3 = cy0.w;
    float cya4 = cy1.x, cya5 = cy1.y, cya6 = cy1.z, cya7 = cy1.w;
    s16x8 g;
#pragma unroll 8
    for (int i = 0; i < 8; ++i) {
        float cy = (i == 0) ? cya0 : (i == 1) ? cya1 : (i == 2) ? cya2 : (i == 3) ? cya3
                 : (i == 4) ? cya4 : (i == 5) ? cya5 : (i == 6) ? cya6 : cya7;
        float h = fmaf(b2f_s(cv[i]), cy, b2f_s(hv[i]));
        g[i] = f2b_s(b2f_s(yv[i]) * h);
    }
    *(s16x8*)(g_out + o) = g;
}

extern "C" void kernel_launch(void* const* d_in, const int* in_sizes, int n_in,
                              void* d_out, int out_size, void* d_ws, size_t ws_size,
                              hipStream_t stream) {
    const float* x    = (const float*)d_in[0];
    const float* Wxy  = (const float*)d_in[1];
    const float* igw  = (const float*)d_in[2];
    const float* igb  = (const float*)d_in[3];
    const float* agw  = (const float*)d_in[4];
    const float* agb  = (const float*)d_in[5];
    const float* apar = (const float*)d_in[6];
    const float* cw   = (const float*)d_in[7];
    const float* cb   = (const float*)d_in[8];
    const float* Wres = (const float*)d_in[9];
    float* out = (float*)d_out;

    // Workspace (187 MiB), lifetime overlays:
    //   [0,32)    xbf  bf16 [M,H]   (dead after GEMM1)  -> hloc bf16 [M,R]
    //   [32,48)   wxyb bf16 [2R,H]  (dead after GEMM1)  -> wT (1 MiB) + sp8 + carry@36
    //   [48,112)  xy   bf16 [M,4096] (xr|gelu(y)); xr dead after gate, y until passB
    //   [112,120) wresb bf16
    //   [120,152) g    bf16 [M,R]  (passB output)
    //   [152,184) cum  bf16 [M,R]
    //   [184,186) AH float2 [B,NCH,R] (packed {cum,h} chunk summaries)
    char* ws = (char*)d_ws;
    const size_t MiB = (size_t)1 << 20;
    bf16*  xbf   = (bf16*)(ws);
    bf16*  hloc  = (bf16*)(ws);               // overlay on xbf
    bf16*  wxyb  = (bf16*)(ws + 32 * MiB);
    bf16*  wT    = (bf16*)(ws + 32 * MiB);    // overlay (staged after GEMM1)
    float* sp8   = (float*)(ws + 33 * MiB + 65536);
    float* cyb   = (float*)(ws + 36 * MiB);   // carry, 4 MiB (region free after GEMM1)
    bf16*  xy    = (bf16*)(ws + 48 * MiB);
    bf16*  wresb = (bf16*)(ws + 112 * MiB);
    bf16*  g     = (bf16*)(ws + 120 * MiB);
    bf16*  cum   = (bf16*)(ws + 152 * MiB);
    float2* AH   = (float2*)(ws + 184 * MiB);

    // merged casts to bf16
    cast_all<<<14336, 256, 0, stream>>>(x, Wxy, Wres, xbf, wxyb, wresb);

    // GEMM1: xy[M,4096] = x[M,2048]*Wxy^T, gelu applied to cols >= 2048.
    // Split into two M-half launches (diagnostic: drops top-5 ceiling to ~64 us so
    // any hidden >64 us kernel surfaces in the profile; cost ~0, 2048 blocks was
    // already 2 scheduling rounds at 4 blocks/CU).
    gemm_bt<bf16><<<dim3(32, 32), 256, 0, stream>>>(xbf, wxyb, xy,
                                                    2048, 2048, 2048, 4096, 2048);
    gemm_bt<bf16><<<dim3(32, 32), 256, 0, stream>>>(xbf + (size_t)4096 * 2048, wxyb,
                                                    xy + (size_t)4096 * 4096,
                                                    2048, 2048, 2048, 4096, 2048);

    // gate prep (after GEMM1 so wT/sp8 can overlay wxyb); sp8 merged into block 32
    wcast_T<<<33, 256, 0, stream>>>(igw, agw, apar, wT, sp8);

    // fused conv + gates + chunk summaries -> hloc (overlays xbf), cum, AH
    gate_kernel<<<dim3(NB_, 128), 256, 0, stream>>>(xy, cw, cb, wT, igb, agb, sp8,
                                                    hloc, cum, AH);

    // carry scan + elementwise passB -> g
    scan_carry<<<16, 256, 0, stream>>>(AH, cyb);
    scan_passB<<<8192, 256, 0, stream>>>(hloc, cum, cyb, xy, g);

    // GEMM2: out[M,H] = g[M,R] * Wres[H,R]^T  (fp32 out, no gelu)
    gemm_bt<float><<<dim3(16, 64), 256, 0, stream>>>(g, wresb, out,
                                                     2048, 2048, 2048, 2048, 1 << 30);
}

// Round 9
// 466.042 us; speedup vs baseline: 1.0268x; 1.0268x over previous
//
#include <hip/hip_runtime.h>
#include <hip/hip_bf16.h>

typedef __hip_bfloat16 bf16;
typedef __attribute__((ext_vector_type(8))) short s16x8;   // 8 bf16 (4 VGPRs) MFMA frag
typedef __attribute__((ext_vector_type(4))) float f32x4;   // MFMA accumulator

#define B_ 2
#define S_ 4096
#define H_ 2048
#define R_ 2048
#define M_ 8192      // B*S
#define NB_ 16
#define BW_ 128
#define CHUNK 64     // scan chunk length
#define NCH 64       // S/CHUNK

__device__ __forceinline__ short f2b_s(float f) {
    return (short)__builtin_bit_cast(unsigned short, __float2bfloat16(f));
}
__device__ __forceinline__ float b2f_s(short s) {
    unsigned int u = ((unsigned int)(unsigned short)s) << 16;
    return __builtin_bit_cast(float, u);
}
__device__ __forceinline__ float sigm_fast(float x) { return 1.f / (1.f + __expf(-x)); }

// async global->LDS, 16B per lane; LDS dest must be wave-uniform base + lane*16
__device__ __forceinline__ void async_g2l(const void* g, void* l) {
    __builtin_amdgcn_global_load_lds((const __attribute__((address_space(1))) void*)g,
                                     (__attribute__((address_space(3))) void*)l, 16, 0, 0);
}

// ------- merged prep: cast x/Wxy/Wres to bf16 + transpose-cast gate weights + sp8 ----
// grid 14369: blocks [0,14336) cast (8 elems/thread); [14336,14368) gate-W transpose
// (strip-wise 32x129 LDS tile, 16.5 KB so cast blocks keep occupancy); 14368 sp8.
// R9: folded wcast_T into cast_all (launch-count 8->6; ~10 us/launch gap theory).
__global__ __launch_bounds__(256) void cast_all(const float* __restrict__ x,
                                                const float* __restrict__ wxy,
                                                const float* __restrict__ wres,
                                                const float* __restrict__ igw,
                                                const float* __restrict__ agw,
                                                const float* __restrict__ apar,
                                                bf16* __restrict__ xbf,
                                                bf16* __restrict__ wxyb,
                                                bf16* __restrict__ wresb,
                                                bf16* __restrict__ wT,
                                                float* __restrict__ sp8) {
    __shared__ float tile[32 * 129];
    int blk = blockIdx.x;
    int tid = threadIdx.x;
    if (blk >= 14336) {
        int b2 = blk - 14336;
        if (b2 == 32) {        // sp8[r] = 8*softplus(a_param[r])
#pragma unroll
            for (int it = 0; it < 8; ++it) {
                int r = it * 256 + tid;
                float ap = apar[r];
                sp8[r] = 8.f * (ap > 20.f ? ap : log1pf(expf(ap)));
            }
            return;
        }
        // wT[p][n][j][i] = w_p[n][i][j], via 4 strips of 32 rows
        int p = b2 >> 4, n = b2 & 15;
        const float* w = (p ? agw : igw) + (size_t)n * 16384;   // [i][j] row-major
        bf16* o = wT + (size_t)b2 * 16384;
        for (int s = 0; s < 4; ++s) {
#pragma unroll
            for (int it = 0; it < 16; ++it) {
                int u = it * 256 + tid;             // r = u>>7 in [0,32), col = u&127
                tile[(u >> 7) * 129 + (u & 127)] = w[(s * 32 + (u >> 7)) * 128 + (u & 127)];
            }
            __syncthreads();
#pragma unroll
            for (int it = 0; it < 16; ++it) {
                int v = it * 256 + tid;             // j = v>>5, ii = v&31
                int j = v >> 5, ii = v & 31;
                o[j * 128 + s * 32 + ii] = __float2bfloat16(tile[ii * 129 + j]);
            }
            __syncthreads();
        }
        return;
    }
    int idx = blk * 256 + tid;
    const float* in; bf16* out; int off;
    if (idx < 2097152)      { in = x;    out = xbf;   off = idx; }
    else if (idx < 3145728) { in = wxy;  out = wxyb;  off = idx - 2097152; }
    else                    { in = wres; out = wresb; off = idx - 3145728; }
    size_t i8 = (size_t)off * 8;
    float4 v0 = *(const float4*)(in + i8);
    float4 v1 = *(const float4*)(in + i8 + 4);
    s16x8 o;
    o[0] = f2b_s(v0.x); o[1] = f2b_s(v0.y); o[2] = f2b_s(v0.z); o[3] = f2b_s(v0.w);
    o[4] = f2b_s(v1.x); o[5] = f2b_s(v1.y); o[6] = f2b_s(v1.z); o[7] = f2b_s(v1.w);
    *(s16x8*)(out + i8) = o;
}

// ---------------- generic NT GEMM: C[M,N] = A[M,K] * B[N,K]^T, bf16 in, OutT out ----
// 128x128 tile, BK=64, 4 waves 2x2, 64x64/wave, 16x16x32 MFMA, XOR-swizzled LDS,
// global_load_lds width=16 staging. launch_bounds(256,4): 4 blocks/CU.
// PROVEN: ~1086 TF at 2048 blocks (R0/R5/R7). R8 MEASURED: 1024-block launches drop
// to ~900 TF (76 us/half; straggler tail + cold-L2 ramp not amortized) -> NEVER
// split; keep grids >= 2048 blocks where possible. GEMM structure FROZEN (R1-R6).
// gelu_from: blocks with nBase >= gelu_from apply exact gelu in the epilogue.
__device__ __forceinline__ void store_c(float* p, float v) { *p = v; }
__device__ __forceinline__ void store_c(bf16* p, float v) { *p = __float2bfloat16(v); }

template <typename OutT>
__global__ __launch_bounds__(256, 4) void gemm_bt(const bf16* __restrict__ A,
                                                  const bf16* __restrict__ Bm,
                                                  OutT* __restrict__ C,
                                                  int K, int lda, int ldb, int ldc,
                                                  int gelu_from) {
    __shared__ __align__(16) short As[128 * 64];
    __shared__ __align__(16) short Bs[128 * 64];
    const int tid = threadIdx.x;
    const int lane = tid & 63, wave = tid >> 6;
    const int waveM = wave >> 1, waveN = wave & 1;
    const int mBase = blockIdx.y * 128, nBase = blockIdx.x * 128;
    const int fm = lane & 15, q = lane >> 4;
    const bool dog = (nBase >= gelu_from);

    f32x4 acc[4][4];
#pragma unroll
    for (int i = 0; i < 4; ++i)
#pragma unroll
        for (int j = 0; j < 4; ++j) acc[i][j] = (f32x4){0.f, 0.f, 0.f, 0.f};

    for (int k0 = 0; k0 < K; k0 += 64) {
        __syncthreads();
#pragma unroll
        for (int it = 0; it < 4; ++it) {
            int off = it * 4096 + tid * 16;          // byte offset in tile (lane-contig)
            int r = off >> 7;                        // row
            int g = ((off & 127) >> 4) ^ (r & 7);    // source k-group for this slot
            async_g2l(A + (size_t)(mBase + r) * lda + k0 + g * 8, (char*)As + off);
            async_g2l(Bm + (size_t)(nBase + r) * ldb + k0 + g * 8, (char*)Bs + off);
        }
        __syncthreads();
#pragma unroll
        for (int s = 0; s < 2; ++s) {
            s16x8 af[4], bfr[4];
#pragma unroll
            for (int i = 0; i < 4; ++i) {
                int row = waveM * 64 + i * 16 + fm;
                af[i] = *(const s16x8*)((char*)As + row * 128 + ((((s << 2) + q) ^ (row & 7)) << 4));
                int col = waveN * 64 + i * 16 + fm;
                bfr[i] = *(const s16x8*)((char*)Bs + col * 128 + ((((s << 2) + q) ^ (col & 7)) << 4));
            }
#pragma unroll
            for (int i = 0; i < 4; ++i)
#pragma unroll
                for (int j = 0; j < 4; ++j)
                    acc[i][j] = __builtin_amdgcn_mfma_f32_16x16x32_bf16(af[i], bfr[j], acc[i][j], 0, 0, 0);
        }
    }
    // C/D layout: col=lane&15, row=q*4+reg (m89/m91-verified)
#pragma unroll
    for (int i = 0; i < 4; ++i) {
        int rowg = mBase + waveM * 64 + i * 16 + q * 4;
#pragma unroll
        for (int j = 0; j < 4; ++j) {
            int colg = nBase + waveN * 64 + j * 16 + fm;
#pragma unroll
            for (int rr = 0; rr < 4; ++rr) {
                float v = acc[i][j][rr];
                if (dog) v = 0.5f * v * (1.f + erff(v * 0.70710678f));
                store_c(C + (size_t)(rowg + rr) * ldc + colg, v);
            }
        }
    }
}

// ------- fused: causal conv + block-diag dual gate GEMM + RG-LRU + chunk scan -------
// grid (NB_, M_/64): one block = one (batch, 64-step chunk, 128-channel block).
// Emits running per-chunk state (hloc_t, cum_t): h_full = hloc + cum*carry.
// Chunk summary packed as float2 {cum, h} for scan_carry.
__global__ __launch_bounds__(256) void gate_kernel(const bf16* __restrict__ xy,
                                                   const float* __restrict__ cw,
                                                   const float* __restrict__ cb,
                                                   const bf16* __restrict__ wT,
                                                   const float* __restrict__ igb,
                                                   const float* __restrict__ agb,
                                                   const float* __restrict__ sp8,
                                                   bf16* __restrict__ hloc_out,
                                                   bf16* __restrict__ cum_out,
                                                   float2* __restrict__ AH) {
    __shared__ __align__(16) short As[64 * 128];     // 16 KB; xc tile -> nx tile -> h tile
    __shared__ __align__(16) char  Wmem[128 * 256];  // 32 KB; Xs raw -> W tile -> a/cum f32
    short* Xs   = (short*)Wmem;                      // 67 rows x 128 shorts (raw xy window)
    short* Ws   = (short*)Wmem;
    float* a_sh = (float*)Wmem;
    const int n = blockIdx.x;
    const int mBase = blockIdx.y * 64;
    const int tid = threadIdx.x;
    const int lane = tid & 63, wave = tid >> 6;
    const int fm = lane & 15, q = lane >> 4;
    const int t0 = mBase & (S_ - 1);

    // 1. stage xy window: rows rr=0..66 <-> m = mBase + rr - 3 (zero outside batch)
#pragma unroll
    for (int it = 0; it < 5; ++it) {
        int u = it * 256 + tid;              // (rr, gg): rr = u>>4, gg = u&15
        if (u < 67 * 16) {
            int rr = u >> 4, gg = u & 15;
            s16x8 v = (s16x8){0, 0, 0, 0, 0, 0, 0, 0};
            if (t0 != 0 || rr >= 3) {
                int m = mBase + rr - 3;
                v = *(const s16x8*)(xy + (size_t)m * 4096 + n * BW_ + gg * 8);
            }
            *(s16x8*)((char*)Xs + u * 16) = v;
        }
    }
    __syncthreads();

    // 2. conv into As (swizzled bf16): thread = (col, row-half), sliding 4-tap window
    {
        int col = tid & 127, rh = tid >> 7;
        int rbase = n * BW_ + col;
        float w0c = cw[rbase], w1c = cw[R_ + rbase], w2c = cw[2 * R_ + rbase],
              w3c = cw[3 * R_ + rbase];
        float bc = cb[rbase];
        int r0 = rh * 32;
        float xm3 = b2f_s(Xs[(r0 + 0) * 128 + col]);
        float xm2 = b2f_s(Xs[(r0 + 1) * 128 + col]);
        float xm1 = b2f_s(Xs[(r0 + 2) * 128 + col]);
#pragma unroll
        for (int rw = 0; rw < 32; ++rw) {
            int row = r0 + rw;
            float x0 = b2f_s(Xs[(row + 3) * 128 + col]);
            float v = bc + w0c * xm3 + w1c * xm2 + w2c * xm1 + w3c * x0;
            xm3 = xm2; xm2 = xm1; xm1 = x0;
            *(short*)((char*)As + row * 256 + ((((col >> 3)) ^ (row & 15)) << 4) +
                      (col & 7) * 2) = f2b_s(v);
        }
    }
    __syncthreads();   // As ready; Xs region dead

    // 3. stage Ws for input gate
    const bf16* w0 = wT + (size_t)n * 16384;
#pragma unroll
    for (int it = 0; it < 8; ++it) {
        int off = it * 4096 + tid * 16;
        int j = off >> 8;
        int g = ((off & 255) >> 4) ^ (j & 15);
        async_g2l(w0 + j * 128 + g * 8, (char*)Ws + off);
    }
    __syncthreads();

    f32x4 accI[8], accA[8];
#pragma unroll
    for (int jj = 0; jj < 8; ++jj) {
        accI[jj] = (f32x4){0.f, 0.f, 0.f, 0.f};
        accA[jj] = (f32x4){0.f, 0.f, 0.f, 0.f};
    }

    const int row = wave * 16 + fm;
#pragma unroll
    for (int s = 0; s < 4; ++s) {
        s16x8 af = *(const s16x8*)((char*)As + row * 256 + ((((s << 2) + q) ^ (row & 15)) << 4));
#pragma unroll
        for (int jj = 0; jj < 8; ++jj) {
            int wrow = jj * 16 + fm;
            s16x8 bw = *(const s16x8*)((char*)Ws + wrow * 256 + ((((s << 2) + q) ^ (wrow & 15)) << 4));
            accI[jj] = __builtin_amdgcn_mfma_f32_16x16x32_bf16(af, bw, accI[jj], 0, 0, 0);
        }
    }
    __syncthreads();  // all waves done reading Ws (gate 1)
    // 4. stage Ws for a gate
    const bf16* w1 = wT + (size_t)(NB_ + n) * 16384;
#pragma unroll
    for (int it = 0; it < 8; ++it) {
        int off = it * 4096 + tid * 16;
        int j = off >> 8;
        int g = ((off & 255) >> 4) ^ (j & 15);
        async_g2l(w1 + j * 128 + g * 8, (char*)Ws + off);
    }
    __syncthreads();
#pragma unroll
    for (int s = 0; s < 4; ++s) {
        s16x8 af = *(const s16x8*)((char*)As + row * 256 + ((((s << 2) + q) ^ (row & 15)) << 4));
#pragma unroll
        for (int jj = 0; jj < 8; ++jj) {
            int wrow = jj * 16 + fm;
            s16x8 bw = *(const s16x8*)((char*)Ws + wrow * 256 + ((((s << 2) + q) ^ (wrow & 15)) << 4));
            accA[jj] = __builtin_amdgcn_mfma_f32_16x16x32_bf16(af, bw, accA[jj], 0, 0, 0);
        }
    }
    __syncthreads();  // MFMA reads of As/Ws done; epilogue may overwrite both

    // 5. epilogue: C/D col=fm, row=q*4+rr. a into a_sh; nx into own As slot.
#pragma unroll
    for (int jj = 0; jj < 8; ++jj) {
        int col = jj * 16 + fm;
        int r = n * BW_ + col;
        float bi = igb[r], ba = agb[r];
        float s8 = sp8[r];
#pragma unroll
        for (int rr = 0; rr < 4; ++rr) {
            int rowl = wave * 16 + q * 4 + rr;
            short* slot = (short*)((char*)As + rowl * 256 +
                          ((((col >> 3)) ^ (rowl & 15)) << 4) + (col & 7) * 2);
            float xcv = b2f_s(*slot);
            float xg = accI[jj][rr] + bi;
            float ag = accA[jj][rr] + ba;
            float la = -s8 * sigm_fast(ag);
            float av = __expf(la);
            float t2 = 2.f * la;
            float nem = (t2 > -0.125f)
                ? -t2 * (1.f + t2 * (0.5f + t2 * (0.16666667f + t2 * 0.04166667f)))
                : 1.f - av * av;
            float nxv = xcv * sigm_fast(xg) * sqrtf(nem);
            short nxs = f2b_s(nxv);
            a_sh[rowl * 128 + col] = av;
            *slot = nxs;                       // same slot this thread read; no race
        }
    }
    __syncthreads();

    // 6. chunk scan (threads 0..127, serial over t): consume a (a_sh) and nx (As),
    //    leave h (bf16) in the As slot and cum (f32) in the a_sh slot (same-thread WAR).
    if (tid < 128) {
        int col = tid;
        float h = 0.f, cum = 1.f;
#pragma unroll 4
        for (int t = 0; t < CHUNK; ++t) {
            short* slot = (short*)((char*)As + t * 256 +
                          ((((col >> 3)) ^ (t & 15)) << 4) + (col & 7) * 2);
            float a = a_sh[t * 128 + col];
            float nxv = b2f_s(*slot);
            h = fmaf(a, h, nxv);
            cum *= a;
            *slot = f2b_s(h);
            a_sh[t * 128 + col] = cum;
        }
        int b = mBase >> 12, c = (mBase & (S_ - 1)) >> 6;
        int so = ((b * NCH + c) << 11) + n * BW_ + col;
        AH[so] = make_float2(cum, h);
    }
    __syncthreads();

    // 7. coalesced emit: unit u = (t, gg): 8 cols gg*8..+7. h granule is one s16x8
    //    (cols of a gg share a 16B granule, order col&7); cum packed from a_sh f32.
#pragma unroll
    for (int it = 0; it < 4; ++it) {
        int u = it * 256 + tid;
        int t = u >> 4, gg = u & 15;
        s16x8 hv = *(const s16x8*)((char*)As + t * 256 + ((gg ^ (t & 15)) << 4));
        s16x8 cv;
#pragma unroll
        for (int i = 0; i < 8; ++i) cv[i] = f2b_s(a_sh[t * 128 + gg * 8 + i]);
        size_t o = (size_t)(mBase + t) * R_ + n * BW_ + gg * 8;
        *(s16x8*)(hloc_out + o) = hv;
        *(s16x8*)(cum_out + o) = cv;
    }
}

// carry into each chunk: 4096 independent 64-step scans; float2-packed summaries,
// batch-8 static-indexed prefetch so the 16 loads issue ahead of the fma chain.
__global__ __launch_bounds__(256) void scan_carry(const float2* __restrict__ AH,
                                                  float* __restrict__ carry) {
    int idx = blockIdx.x * 256 + threadIdx.x;  // B*R = 4096
    int r = idx & (R_ - 1), b = idx >> 11;
    int base = b * NCH * R_ + r;
    float cy = 0.f;
    for (int c0 = 0; c0 < NCH; c0 += 8) {
        float2 v[8];
#pragma unroll
        for (int j = 0; j < 8; ++j) v[j] = AH[base + (c0 + j) * R_];
#pragma unroll
        for (int j = 0; j < 8; ++j) {
            carry[base + (c0 + j) * R_] = cy;
            cy = fmaf(v[j].x, cy, v[j].y);
        }
    }
}

// passB (elementwise): h_full = hloc + cum*carry; g = ygelu * h_full -> bf16.
// y columns of xy already hold gelu(y) (applied in GEMM1 epilogue) -> no erf here.
__global__ __launch_bounds__(256) void scan_passB(const bf16* __restrict__ hloc,
                                                  const bf16* __restrict__ cum,
                                                  const float* __restrict__ carry,
                                                  const bf16* __restrict__ xy,
                                                  bf16* __restrict__ g_out) {
    int idx = blockIdx.x * 256 + threadIdx.x;   // M*R/8 = 2097152 units
    int m = idx >> 8;                           // row
    int r = (idx & 255) << 3;                   // col*8
    int b = m >> 12, c = (m & 4095) >> 6;
    int so = ((b * NCH + c) << 11) + r;
    size_t o = (size_t)m * R_ + r;
    s16x8 hv = *(const s16x8*)(hloc + o);
    s16x8 cv = *(const s16x8*)(cum + o);
    float4 cy0 = *(const float4*)(carry + so);
    float4 cy1 = *(const float4*)(carry + so + 4);
    s16x8 yv = *(const s16x8*)(xy + (size_t)m * 4096 + 2048 + r);
    float cya0 = cy0.x, cya1 = cy0.y, cya2 = cy0.z, cya3 = cy0.w;
    float cya4 = cy1.x, cya5 = cy1.y, cya6 = cy1.z, cya7 = cy1.w;
    s16x8 g;
#pragma unroll 8
    for (int i = 0; i < 8; ++i) {
        float cy = (i == 0) ? cya0 : (i == 1) ? cya1 : (i == 2) ? cya2 : (i == 3) ? cya3
                 : (i == 4) ? cya4 : (i == 5) ? cya5 : (i == 6) ? cya6 : cya7;
        float h = fmaf(b2f_s(cv[i]), cy, b2f_s(hv[i]));
        g[i] = f2b_s(b2f_s(yv[i]) * h);
    }
    *(s16x8*)(g_out + o) = g;
}

extern "C" void kernel_launch(void* const* d_in, const int* in_sizes, int n_in,
                              void* d_out, int out_size, void* d_ws, size_t ws_size,
                              hipStream_t stream) {
    const float* x    = (const float*)d_in[0];
    const float* Wxy  = (const float*)d_in[1];
    const float* igw  = (const float*)d_in[2];
    const float* igb  = (const float*)d_in[3];
    const float* agw  = (const float*)d_in[4];
    const float* agb  = (const float*)d_in[5];
    const float* apar = (const float*)d_in[6];
    const float* cw   = (const float*)d_in[7];
    const float* cb   = (const float*)d_in[8];
    const float* Wres = (const float*)d_in[9];
    float* out = (float*)d_out;

    // Workspace (187 MiB), lifetime overlays:
    //   [0,32)    xbf  bf16 [M,H]   (dead after GEMM1)  -> hloc bf16 [M,R]
    //   [32,48)   wxyb bf16 [2R,H]  (dead after GEMM1)  -> carry fp32 @36
    //   [48,112)  xy   bf16 [M,4096] (xr|gelu(y)); xr dead after gate, y until passB
    //   [112,120) wresb bf16
    //   [120,152) wT (1 MiB @120) + sp8 (@121, both dead after gate) -> g bf16 [M,R]
    //   [152,184) cum  bf16 [M,R]
    //   [184,186) AH float2 [B,NCH,R] (packed {cum,h} chunk summaries)
    char* ws = (char*)d_ws;
    const size_t MiB = (size_t)1 << 20;
    bf16*  xbf   = (bf16*)(ws);
    bf16*  hloc  = (bf16*)(ws);               // overlay on xbf
    bf16*  wxyb  = (bf16*)(ws + 32 * MiB);
    float* cyb   = (float*)(ws + 36 * MiB);   // carry, 1 MiB (wxyb dead after GEMM1)
    bf16*  xy    = (bf16*)(ws + 48 * MiB);
    bf16*  wresb = (bf16*)(ws + 112 * MiB);
    bf16*  wT    = (bf16*)(ws + 120 * MiB);   // dead after gate; g overlays
    float* sp8   = (float*)(ws + 121 * MiB);
    bf16*  g     = (bf16*)(ws + 120 * MiB);   // passB output (after wT dead)
    bf16*  cum   = (bf16*)(ws + 152 * MiB);
    float2* AH   = (float2*)(ws + 184 * MiB);

    // merged prep: casts + gate-W transpose + sp8 (wT/sp8 live outside GEMM1 regions)
    cast_all<<<14369, 256, 0, stream>>>(x, Wxy, Wres, igw, agw, apar,
                                        xbf, wxyb, wresb, wT, sp8);

    // GEMM1 (single 2048-block launch; R8 measured splitting costs 17%):
    // xy[M,4096] = x*Wxy^T, gelu applied to cols >= 2048
    gemm_bt<bf16><<<dim3(32, 64), 256, 0, stream>>>(xbf, wxyb, xy,
                                                    2048, 2048, 2048, 4096, 2048);

    // fused conv + gates + chunk summaries -> hloc (overlays xbf), cum, AH
    gate_kernel<<<dim3(NB_, 128), 256, 0, stream>>>(xy, cw, cb, wT, igb, agb, sp8,
                                                    hloc, cum, AH);

    // carry scan + elementwise passB -> g (overlays wT, dead by now)
    scan_carry<<<16, 256, 0, stream>>>(AH, cyb);
    scan_passB<<<8192, 256, 0, stream>>>(hloc, cum, cyb, xy, g);

    // GEMM2: out[M,H] = g[M,R] * Wres[H,R]^T  (fp32 out, no gelu)
    gemm_bt<float><<<dim3(16, 64), 256, 0, stream>>>(g, wresb, out,
                                                     2048, 2048, 2048, 2048, 1 << 30);
}

// Round 10
// 452.333 us; speedup vs baseline: 1.0580x; 1.0303x over previous
//
#include <hip/hip_runtime.h>
#include <hip/hip_bf16.h>

typedef __hip_bfloat16 bf16;
typedef __attribute__((ext_vector_type(8))) short s16x8;   // 8 bf16 (4 VGPRs) MFMA frag
typedef __attribute__((ext_vector_type(4))) float f32x4;   // MFMA accumulator

#define B_ 2
#define S_ 4096
#define H_ 2048
#define R_ 2048
#define M_ 8192      // B*S
#define NB_ 16
#define BW_ 128
#define CHUNK 64     // scan chunk length
#define NCH 64       // S/CHUNK

__device__ __forceinline__ short f2b_s(float f) {
    return (short)__builtin_bit_cast(unsigned short, __float2bfloat16(f));
}
__device__ __forceinline__ float b2f_s(short s) {
    unsigned int u = ((unsigned int)(unsigned short)s) << 16;
    return __builtin_bit_cast(float, u);
}
__device__ __forceinline__ float sigm_fast(float x) { return 1.f / (1.f + __expf(-x)); }

// async global->LDS, 16B per lane; LDS dest must be wave-uniform base + lane*16
__device__ __forceinline__ void async_g2l(const void* g, void* l) {
    __builtin_amdgcn_global_load_lds((const __attribute__((address_space(1))) void*)g,
                                     (__attribute__((address_space(3))) void*)l, 16, 0, 0);
}

// ------- merged prep: cast x/Wxy/Wres to bf16 + transpose-cast gate weights + sp8 ----
// grid 14369: blocks [0,14336) cast (8 elems/thread); [14336,14368) gate-W transpose
// (strip-wise 32x129 LDS tile); 14368 sp8. (R9 launch merge, kept.)
__global__ __launch_bounds__(256) void cast_all(const float* __restrict__ x,
                                                const float* __restrict__ wxy,
                                                const float* __restrict__ wres,
                                                const float* __restrict__ igw,
                                                const float* __restrict__ agw,
                                                const float* __restrict__ apar,
                                                bf16* __restrict__ xbf,
                                                bf16* __restrict__ wxyb,
                                                bf16* __restrict__ wresb,
                                                bf16* __restrict__ wT,
                                                float* __restrict__ sp8) {
    __shared__ float tile[32 * 129];
    int blk = blockIdx.x;
    int tid = threadIdx.x;
    if (blk >= 14336) {
        int b2 = blk - 14336;
        if (b2 == 32) {        // sp8[r] = 8*softplus(a_param[r])
#pragma unroll
            for (int it = 0; it < 8; ++it) {
                int r = it * 256 + tid;
                float ap = apar[r];
                sp8[r] = 8.f * (ap > 20.f ? ap : log1pf(expf(ap)));
            }
            return;
        }
        // wT[p][n][j][i] = w_p[n][i][j], via 4 strips of 32 rows
        int p = b2 >> 4, n = b2 & 15;
        const float* w = (p ? agw : igw) + (size_t)n * 16384;   // [i][j] row-major
        bf16* o = wT + (size_t)b2 * 16384;
        for (int s = 0; s < 4; ++s) {
#pragma unroll
            for (int it = 0; it < 16; ++it) {
                int u = it * 256 + tid;             // r = u>>7 in [0,32), col = u&127
                tile[(u >> 7) * 129 + (u & 127)] = w[(s * 32 + (u >> 7)) * 128 + (u & 127)];
            }
            __syncthreads();
#pragma unroll
            for (int it = 0; it < 16; ++it) {
                int v = it * 256 + tid;             // j = v>>5, ii = v&31
                int j = v >> 5, ii = v & 31;
                o[j * 128 + s * 32 + ii] = __float2bfloat16(tile[ii * 129 + j]);
            }
            __syncthreads();
        }
        return;
    }
    int idx = blk * 256 + tid;
    const float* in; bf16* out; int off;
    if (idx < 2097152)      { in = x;    out = xbf;   off = idx; }
    else if (idx < 3145728) { in = wxy;  out = wxyb;  off = idx - 2097152; }
    else                    { in = wres; out = wresb; off = idx - 3145728; }
    size_t i8 = (size_t)off * 8;
    float4 v0 = *(const float4*)(in + i8);
    float4 v1 = *(const float4*)(in + i8 + 4);
    s16x8 o;
    o[0] = f2b_s(v0.x); o[1] = f2b_s(v0.y); o[2] = f2b_s(v0.z); o[3] = f2b_s(v0.w);
    o[4] = f2b_s(v1.x); o[5] = f2b_s(v1.y); o[6] = f2b_s(v1.z); o[7] = f2b_s(v1.w);
    *(s16x8*)(out + i8) = o;
}

// ---------------- gemm_bt: C[M,N] = A[M,K]*B[N,K]^T, 128x128 tile ----------------
// PROVEN BEST for GEMM1 (2048 blocks: 126.5 us, 1086 TF, MfmaUtil 52%). R8: at 1024
// blocks drops to ~900 TF (straggler tail) -> use ONLY for grids >= 2048 blocks.
// R9: gelu-in-epilogue cost +14.4 us (erff runs AFTER the K-loop, no MFMA shadow) —
// removed; gelu lives in passB.
__device__ __forceinline__ void store_c(float* p, float v) { *p = v; }
__device__ __forceinline__ void store_c(bf16* p, float v) { *p = __float2bfloat16(v); }

template <typename OutT>
__global__ __launch_bounds__(256, 4) void gemm_bt(const bf16* __restrict__ A,
                                                  const bf16* __restrict__ Bm,
                                                  OutT* __restrict__ C,
                                                  int K, int lda, int ldb, int ldc) {
    __shared__ __align__(16) short As[128 * 64];
    __shared__ __align__(16) short Bs[128 * 64];
    const int tid = threadIdx.x;
    const int lane = tid & 63, wave = tid >> 6;
    const int waveM = wave >> 1, waveN = wave & 1;
    const int mBase = blockIdx.y * 128, nBase = blockIdx.x * 128;
    const int fm = lane & 15, q = lane >> 4;

    f32x4 acc[4][4];
#pragma unroll
    for (int i = 0; i < 4; ++i)
#pragma unroll
        for (int j = 0; j < 4; ++j) acc[i][j] = (f32x4){0.f, 0.f, 0.f, 0.f};

    for (int k0 = 0; k0 < K; k0 += 64) {
        __syncthreads();
#pragma unroll
        for (int it = 0; it < 4; ++it) {
            int off = it * 4096 + tid * 16;          // byte offset in tile (lane-contig)
            int r = off >> 7;                        // row
            int g = ((off & 127) >> 4) ^ (r & 7);    // source k-group for this slot
            async_g2l(A + (size_t)(mBase + r) * lda + k0 + g * 8, (char*)As + off);
            async_g2l(Bm + (size_t)(nBase + r) * ldb + k0 + g * 8, (char*)Bs + off);
        }
        __syncthreads();
#pragma unroll
        for (int s = 0; s < 2; ++s) {
            s16x8 af[4], bfr[4];
#pragma unroll
            for (int i = 0; i < 4; ++i) {
                int row = waveM * 64 + i * 16 + fm;
                af[i] = *(const s16x8*)((char*)As + row * 128 + ((((s << 2) + q) ^ (row & 7)) << 4));
                int col = waveN * 64 + i * 16 + fm;
                bfr[i] = *(const s16x8*)((char*)Bs + col * 128 + ((((s << 2) + q) ^ (col & 7)) << 4));
            }
#pragma unroll
            for (int i = 0; i < 4; ++i)
#pragma unroll
                for (int j = 0; j < 4; ++j)
                    acc[i][j] = __builtin_amdgcn_mfma_f32_16x16x32_bf16(af[i], bfr[j], acc[i][j], 0, 0, 0);
        }
    }
    // C/D layout: col=lane&15, row=q*4+reg (m89/m91-verified)
#pragma unroll
    for (int i = 0; i < 4; ++i) {
        int rowg = mBase + waveM * 64 + i * 16 + q * 4;
#pragma unroll
        for (int j = 0; j < 4; ++j) {
            int colg = nBase + waveN * 64 + j * 16 + fm;
#pragma unroll
            for (int rr = 0; rr < 4; ++rr)
                store_c(C + (size_t)(rowg + rr) * ldc + colg, acc[i][j][rr]);
        }
    }
}

// ---------------- gemm256: 256x256 8-phase pipelined NT GEMM (R6 form) ----------------
// PROVEN BEST for GEMM2 (256-block launch = exactly 1 block/CU, no multi-round
// scheduling tail; R6 total beat gemm_bt-GEMM2 by ~14 us). gemm_bt at 1024 blocks
// is ~900 TF (R8); this kernel keeps ~1100 TF at 1 block/CU. Use for 256-block grids.
#define MFMA16(Q)                                                                     \
    _Pragma("unroll") for (int j = 0; j < 4; ++j) {                                   \
        acc[2*(Q)][j]   = __builtin_amdgcn_mfma_f32_16x16x32_bf16(af[0][0], bfr[j][0], acc[2*(Q)][j], 0, 0, 0);   \
        acc[2*(Q)][j]   = __builtin_amdgcn_mfma_f32_16x16x32_bf16(af[0][1], bfr[j][1], acc[2*(Q)][j], 0, 0, 0);   \
        acc[2*(Q)+1][j] = __builtin_amdgcn_mfma_f32_16x16x32_bf16(af[1][0], bfr[j][0], acc[2*(Q)+1][j], 0, 0, 0); \
        acc[2*(Q)+1][j] = __builtin_amdgcn_mfma_f32_16x16x32_bf16(af[1][1], bfr[j][1], acc[2*(Q)+1][j], 0, 0, 0); \
    }

#define PHASE(BASEP, Q, LOADB, STMTS, VMSTMT)                                         \
    rdA2(BASEP, Q, af);                                                               \
    if (LOADB) rdB8(BASEP, bfr);                                                      \
    STMTS;                                                                            \
    if (LOADB) asm volatile("s_waitcnt lgkmcnt(8)" ::: "memory");                     \
    __builtin_amdgcn_s_barrier();                                                     \
    asm volatile("s_waitcnt lgkmcnt(0)" ::: "memory");                                \
    __builtin_amdgcn_sched_barrier(0);                                                \
    __builtin_amdgcn_s_setprio(1);                                                    \
    MFMA16(Q);                                                                        \
    __builtin_amdgcn_s_setprio(0);                                                    \
    VMSTMT;                                                                           \
    __builtin_amdgcn_s_barrier();                                                     \
    __builtin_amdgcn_sched_barrier(0);

template <typename OutT>
__global__ __launch_bounds__(512, 2) void gemm256(const bf16* __restrict__ A,
                                                  const bf16* __restrict__ Bm,
                                                  OutT* __restrict__ C,
                                                  int K, int lda, int ldb, int ldc) {
    extern __shared__ __align__(16) char lds[];
    const int tid = threadIdx.x;
    const int lane = tid & 63, wave = tid >> 6;
    const int wm = wave >> 2, wn = wave & 3;
    const int fm = lane & 15, q = lane >> 4;
    const int mBase = blockIdx.y * 256, nBase = blockIdx.x * 256;
    const int NT = K >> 6, LT = (NT >> 1) - 1;

    auto stage_half = [&](int tile, int hh) {
        if (tile >= NT) return;
        const bf16* src = (hh < 2) ? Bm : A;
        const int ld = (hh < 2) ? ldb : lda;
        const int rowBase = ((hh < 2) ? nBase : mBase) + ((hh & 1) << 7);
        char* dst = lds + ((tile & 1) << 16) + ((hh < 2) ? 32768 : 0) + ((hh & 1) << 14);
#pragma unroll
        for (int rnd = 0; rnd < 2; ++rnd) {
            int off = rnd * 8192 + tid * 16;
            int r = off >> 7;                        // row within half, 0..127
            int g = ((off >> 4) & 7) ^ (r & 7);      // source k-group for this slot
            async_g2l(src + (size_t)(rowBase + r) * ld + tile * 64 + g * 8, dst + off);
        }
    };
    auto rdA2 = [&](const char* base, int qp, s16x8 (&dst)[2][2]) {
#pragma unroll
        for (int i2 = 0; i2 < 2; ++i2) {
            int r7 = (qp * 2 + i2) * 16 + fm;        // row within own half
            const char* p = base + (wm << 14) + r7 * 128;
#pragma unroll
            for (int kk = 0; kk < 2; ++kk)
                dst[i2][kk] = *(const s16x8*)(p + ((((kk << 2) + q) ^ (r7 & 7)) << 4));
        }
    };
    auto rdB8 = [&](const char* base, s16x8 (&dst)[4][2]) {
#pragma unroll
        for (int j = 0; j < 4; ++j) {
            int col = wn * 64 + j * 16 + fm;
            const char* p = base + 32768 + ((col >> 7) << 14) + (col & 127) * 128;
#pragma unroll
            for (int kk = 0; kk < 2; ++kk)
                dst[j][kk] = *(const s16x8*)(p + ((((kk << 2) + q) ^ (col & 7)) << 4));
        }
    };

    s16x8 af[2][2], bfr[4][2];
    f32x4 acc[8][4];
#pragma unroll
    for (int i = 0; i < 8; ++i)
#pragma unroll
        for (int j = 0; j < 4; ++j) acc[i][j] = (f32x4){0.f, 0.f, 0.f, 0.f};

    stage_half(0, 0); stage_half(0, 1); stage_half(0, 2); stage_half(0, 3);
    stage_half(1, 0); stage_half(1, 1);
    asm volatile("s_waitcnt vmcnt(4)" ::: "memory");
    __builtin_amdgcn_s_barrier();
    __builtin_amdgcn_sched_barrier(0);

    for (int t = 0; t <= LT; ++t) {
        const int Ta = 2 * t, Tb = Ta + 1;
        const char* b0 = lds;            // Ta even -> buf0
        const char* b1 = lds + 65536;    // Tb -> buf1

        PHASE(b0, 0, 1, { stage_half(Tb, 2); }, {})
        PHASE(b0, 1, 0, { stage_half(Tb, 3); stage_half(Ta + 2, 0); }, {})
        PHASE(b0, 2, 0, { stage_half(Ta + 2, 1); }, {})
        PHASE(b0, 3, 0, {},
              { if (t < LT) asm volatile("s_waitcnt vmcnt(4)" ::: "memory");
                else        asm volatile("s_waitcnt vmcnt(0)" ::: "memory"); })

        PHASE(b1, 0, 1, { stage_half(Ta + 2, 2); }, {})
        PHASE(b1, 1, 0, { stage_half(Ta + 2, 3); stage_half(Tb + 2, 0); }, {})
        PHASE(b1, 2, 0, { stage_half(Tb + 2, 1); }, {})
        PHASE(b1, 3, 0, {},
              { if (t < LT) asm volatile("s_waitcnt vmcnt(4)" ::: "memory");
                else        asm volatile("s_waitcnt vmcnt(0)" ::: "memory"); })
    }

    // C/D layout: col=lane&15, row=q*4+reg (m89/m91-verified)
#pragma unroll
    for (int i = 0; i < 8; ++i) {
        int rowg = mBase + wm * 128 + i * 16 + q * 4;
#pragma unroll
        for (int j = 0; j < 4; ++j) {
            int colg = nBase + wn * 64 + j * 16 + fm;
#pragma unroll
            for (int rr = 0; rr < 4; ++rr)
                store_c(C + (size_t)(rowg + rr) * ldc + colg, acc[i][j][rr]);
        }
    }
}

// ------- fused: causal conv + block-diag dual gate GEMM + RG-LRU + chunk scan -------
// grid (NB_, M_/64): one block = one (batch, 64-step chunk, 128-channel block).
// Emits running per-chunk state (hloc_t, cum_t): h_full = hloc + cum*carry.
__global__ __launch_bounds__(256) void gate_kernel(const bf16* __restrict__ xy,
                                                   const float* __restrict__ cw,
                                                   const float* __restrict__ cb,
                                                   const bf16* __restrict__ wT,
                                                   const float* __restrict__ igb,
                                                   const float* __restrict__ agb,
                                                   const float* __restrict__ sp8,
                                                   bf16* __restrict__ hloc_out,
                                                   bf16* __restrict__ cum_out,
                                                   float2* __restrict__ AH) {
    __shared__ __align__(16) short As[64 * 128];     // 16 KB; xc tile -> nx tile -> h tile
    __shared__ __align__(16) char  Wmem[128 * 256];  // 32 KB; Xs raw -> W tile -> a/cum f32
    short* Xs   = (short*)Wmem;                      // 67 rows x 128 shorts (raw xy window)
    short* Ws   = (short*)Wmem;
    float* a_sh = (float*)Wmem;
    const int n = blockIdx.x;
    const int mBase = blockIdx.y * 64;
    const int tid = threadIdx.x;
    const int lane = tid & 63, wave = tid >> 6;
    const int fm = lane & 15, q = lane >> 4;
    const int t0 = mBase & (S_ - 1);

    // 1. stage xy window: rows rr=0..66 <-> m = mBase + rr - 3 (zero outside batch)
#pragma unroll
    for (int it = 0; it < 5; ++it) {
        int u = it * 256 + tid;              // (rr, gg): rr = u>>4, gg = u&15
        if (u < 67 * 16) {
            int rr = u >> 4, gg = u & 15;
            s16x8 v = (s16x8){0, 0, 0, 0, 0, 0, 0, 0};
            if (t0 != 0 || rr >= 3) {
                int m = mBase + rr - 3;
                v = *(const s16x8*)(xy + (size_t)m * 4096 + n * BW_ + gg * 8);
            }
            *(s16x8*)((char*)Xs + u * 16) = v;
        }
    }
    __syncthreads();

    // 2. conv into As (swizzled bf16): thread = (col, row-half), sliding 4-tap window
    {
        int col = tid & 127, rh = tid >> 7;
        int rbase = n * BW_ + col;
        float w0c = cw[rbase], w1c = cw[R_ + rbase], w2c = cw[2 * R_ + rbase],
              w3c = cw[3 * R_ + rbase];
        float bc = cb[rbase];
        int r0 = rh * 32;
        float xm3 = b2f_s(Xs[(r0 + 0) * 128 + col]);
        float xm2 = b2f_s(Xs[(r0 + 1) * 128 + col]);
        float xm1 = b2f_s(Xs[(r0 + 2) * 128 + col]);
#pragma unroll
        for (int rw = 0; rw < 32; ++rw) {
            int row = r0 + rw;
            float x0 = b2f_s(Xs[(row + 3) * 128 + col]);
            float v = bc + w0c * xm3 + w1c * xm2 + w2c * xm1 + w3c * x0;
            xm3 = xm2; xm2 = xm1; xm1 = x0;
            *(short*)((char*)As + row * 256 + ((((col >> 3)) ^ (row & 15)) << 4) +
                      (col & 7) * 2) = f2b_s(v);
        }
    }
    __syncthreads();   // As ready; Xs region dead

    // 3. stage Ws for input gate
    const bf16* w0 = wT + (size_t)n * 16384;
#pragma unroll
    for (int it = 0; it < 8; ++it) {
        int off = it * 4096 + tid * 16;
        int j = off >> 8;
        int g = ((off & 255) >> 4) ^ (j & 15);
        async_g2l(w0 + j * 128 + g * 8, (char*)Ws + off);
    }
    __syncthreads();

    f32x4 accI[8], accA[8];
#pragma unroll
    for (int jj = 0; jj < 8; ++jj) {
        accI[jj] = (f32x4){0.f, 0.f, 0.f, 0.f};
        accA[jj] = (f32x4){0.f, 0.f, 0.f, 0.f};
    }

    const int row = wave * 16 + fm;
#pragma unroll
    for (int s = 0; s < 4; ++s) {
        s16x8 af = *(const s16x8*)((char*)As + row * 256 + ((((s << 2) + q) ^ (row & 15)) << 4));
#pragma unroll
        for (int jj = 0; jj < 8; ++jj) {
            int wrow = jj * 16 + fm;
            s16x8 bw = *(const s16x8*)((char*)Ws + wrow * 256 + ((((s << 2) + q) ^ (wrow & 15)) << 4));
            accI[jj] = __builtin_amdgcn_mfma_f32_16x16x32_bf16(af, bw, accI[jj], 0, 0, 0);
        }
    }
    __syncthreads();  // all waves done reading Ws (gate 1)
    // 4. stage Ws for a gate
    const bf16* w1 = wT + (size_t)(NB_ + n) * 16384;
#pragma unroll
    for (int it = 0; it < 8; ++it) {
        int off = it * 4096 + tid * 16;
        int j = off >> 8;
        int g = ((off & 255) >> 4) ^ (j & 15);
        async_g2l(w1 + j * 128 + g * 8, (char*)Ws + off);
    }
    __syncthreads();
#pragma unroll
    for (int s = 0; s < 4; ++s) {
        s16x8 af = *(const s16x8*)((char*)As + row * 256 + ((((s << 2) + q) ^ (row & 15)) << 4));
#pragma unroll
        for (int jj = 0; jj < 8; ++jj) {
            int wrow = jj * 16 + fm;
            s16x8 bw = *(const s16x8*)((char*)Ws + wrow * 256 + ((((s << 2) + q) ^ (wrow & 15)) << 4));
            accA[jj] = __builtin_amdgcn_mfma_f32_16x16x32_bf16(af, bw, accA[jj], 0, 0, 0);
        }
    }
    __syncthreads();  // MFMA reads of As/Ws done; epilogue may overwrite both

    // 5. epilogue: C/D col=fm, row=q*4+rr. a into a_sh; nx into own As slot.
#pragma unroll
    for (int jj = 0; jj < 8; ++jj) {
        int col = jj * 16 + fm;
        int r = n * BW_ + col;
        float bi = igb[r], ba = agb[r];
        float s8 = sp8[r];
#pragma unroll
        for (int rr = 0; rr < 4; ++rr) {
            int rowl = wave * 16 + q * 4 + rr;
            short* slot = (short*)((char*)As + rowl * 256 +
                          ((((col >> 3)) ^ (rowl & 15)) << 4) + (col & 7) * 2);
            float xcv = b2f_s(*slot);
            float xg = accI[jj][rr] + bi;
            float ag = accA[jj][rr] + ba;
            float la = -s8 * sigm_fast(ag);
            float av = __expf(la);
            float t2 = 2.f * la;
            float nem = (t2 > -0.125f)
                ? -t2 * (1.f + t2 * (0.5f + t2 * (0.16666667f + t2 * 0.04166667f)))
                : 1.f - av * av;
            float nxv = xcv * sigm_fast(xg) * sqrtf(nem);
            short nxs = f2b_s(nxv);
            a_sh[rowl * 128 + col] = av;
            *slot = nxs;                       // same slot this thread read; no race
        }
    }
    __syncthreads();

    // 6. chunk scan (threads 0..127, serial over t): consume a (a_sh) and nx (As),
    //    leave h (bf16) in the As slot and cum (f32) in the a_sh slot (same-thread WAR).
    if (tid < 128) {
        int col = tid;
        float h = 0.f, cum = 1.f;
#pragma unroll 4
        for (int t = 0; t < CHUNK; ++t) {
            short* slot = (short*)((char*)As + t * 256 +
                          ((((col >> 3)) ^ (t & 15)) << 4) + (col & 7) * 2);
            float a = a_sh[t * 128 + col];
            float nxv = b2f_s(*slot);
            h = fmaf(a, h, nxv);
            cum *= a;
            *slot = f2b_s(h);
            a_sh[t * 128 + col] = cum;
        }
        int b = mBase >> 12, c = (mBase & (S_ - 1)) >> 6;
        int so = ((b * NCH + c) << 11) + n * BW_ + col;
        AH[so] = make_float2(cum, h);
    }
    __syncthreads();

    // 7. coalesced emit: unit u = (t, gg): 8 cols gg*8..+7. h granule is one s16x8;
    //    cum packed from a_sh f32.
#pragma unroll
    for (int it = 0; it < 4; ++it) {
        int u = it * 256 + tid;
        int t = u >> 4, gg = u & 15;
        s16x8 hv = *(const s16x8*)((char*)As + t * 256 + ((gg ^ (t & 15)) << 4));
        s16x8 cv;
#pragma unroll
        for (int i = 0; i < 8; ++i) cv[i] = f2b_s(a_sh[t * 128 + gg * 8 + i]);
        size_t o = (size_t)(mBase + t) * R_ + n * BW_ + gg * 8;
        *(s16x8*)(hloc_out + o) = hv;
        *(s16x8*)(cum_out + o) = cv;
    }
}

// carry into each chunk: 4096 independent 64-step scans; float2-packed summaries,
// batch-8 static-indexed prefetch so the 16 loads issue ahead of the fma chain.
__global__ __launch_bounds__(256) void scan_carry(const float2* __restrict__ AH,
                                                  float* __restrict__ carry) {
    int idx = blockIdx.x * 256 + threadIdx.x;  // B*R = 4096
    int r = idx & (R_ - 1), b = idx >> 11;
    int base = b * NCH * R_ + r;
    float cy = 0.f;
    for (int c0 = 0; c0 < NCH; c0 += 8) {
        float2 v[8];
#pragma unroll
        for (int j = 0; j < 8; ++j) v[j] = AH[base + (c0 + j) * R_];
#pragma unroll
        for (int j = 0; j < 8; ++j) {
            carry[base + (c0 + j) * R_] = cy;
            cy = fmaf(v[j].x, cy, v[j].y);
        }
    }
}

// passB (elementwise): h_full = hloc + cum*carry; g = gelu_exact(y)*h_full -> bf16.
// (R9 measured: erf belongs HERE, not in the GEMM epilogue — +14.4 us there.)
__global__ __launch_bounds__(256) void scan_passB(const bf16* __restrict__ hloc,
                                                  const bf16* __restrict__ cum,
                                                  const float* __restrict__ carry,
                                                  const bf16* __restrict__ xy,
                                                  bf16* __restrict__ g_out) {
    int idx = blockIdx.x * 256 + threadIdx.x;   // M*R/8 = 2097152 units
    int m = idx >> 8;                           // row
    int r = (idx & 255) << 3;                   // col*8
    int b = m >> 12, c = (m & 4095) >> 6;
    int so = ((b * NCH + c) << 11) + r;
    size_t o = (size_t)m * R_ + r;
    s16x8 hv = *(const s16x8*)(hloc + o);
    s16x8 cv = *(const s16x8*)(cum + o);
    float4 cy0 = *(const float4*)(carry + so);
    float4 cy1 = *(const float4*)(carry + so + 4);
    s16x8 yv = *(const s16x8*)(xy + (size_t)m * 4096 + 2048 + r);
    float cya0 = cy0.x, cya1 = cy0.y, cya2 = cy0.z, cya3 = cy0.w;
    float cya4 = cy1.x, cya5 = cy1.y, cya6 = cy1.z, cya7 = cy1.w;
    s16x8 g;
#pragma unroll 8
    for (int i = 0; i < 8; ++i) {
        float cy = (i == 0) ? cya0 : (i == 1) ? cya1 : (i == 2) ? cya2 : (i == 3) ? cya3
                 : (i == 4) ? cya4 : (i == 5) ? cya5 : (i == 6) ? cya6 : cya7;
        float h = fmaf(b2f_s(cv[i]), cy, b2f_s(hv[i]));
        float y = b2f_s(yv[i]);
        float gg = 0.5f * y * (1.f + erff(y * 0.70710678f));
        g[i] = f2b_s(gg * h);
    }
    *(s16x8*)(g_out + o) = g;
}

extern "C" void kernel_launch(void* const* d_in, const int* in_sizes, int n_in,
                              void* d_out, int out_size, void* d_ws, size_t ws_size,
                              hipStream_t stream) {
    const float* x    = (const float*)d_in[0];
    const float* Wxy  = (const float*)d_in[1];
    const float* igw  = (const float*)d_in[2];
    const float* igb  = (const float*)d_in[3];
    const float* agw  = (const float*)d_in[4];
    const float* agb  = (const float*)d_in[5];
    const float* apar = (const float*)d_in[6];
    const float* cw   = (const float*)d_in[7];
    const float* cb   = (const float*)d_in[8];
    const float* Wres = (const float*)d_in[9];
    float* out = (float*)d_out;

    // Workspace (187 MiB), lifetime overlays:
    //   [0,32)    xbf  bf16 [M,H]   (dead after GEMM1)  -> hloc bf16 [M,R]
    //   [32,48)   wxyb bf16 [2R,H]  (dead after GEMM1)  -> carry fp32 @36
    //   [48,112)  xy   bf16 [M,4096] (xr|y); xr dead after gate, y until passB
    //   [112,120) wresb bf16
    //   [120,152) wT (1 MiB @120) + sp8 (@121, dead after gate) -> g bf16 [M,R]
    //   [152,184) cum  bf16 [M,R]
    //   [184,186) AH float2 [B,NCH,R] (packed {cum,h} chunk summaries)
    char* ws = (char*)d_ws;
    const size_t MiB = (size_t)1 << 20;
    bf16*  xbf   = (bf16*)(ws);
    bf16*  hloc  = (bf16*)(ws);               // overlay on xbf
    bf16*  wxyb  = (bf16*)(ws + 32 * MiB);
    float* cyb   = (float*)(ws + 36 * MiB);   // carry (wxyb dead after GEMM1)
    bf16*  xy    = (bf16*)(ws + 48 * MiB);
    bf16*  wresb = (bf16*)(ws + 112 * MiB);
    bf16*  wT    = (bf16*)(ws + 120 * MiB);   // dead after gate; g overlays
    float* sp8   = (float*)(ws + 121 * MiB);
    bf16*  g     = (bf16*)(ws + 120 * MiB);   // passB output (after wT dead)
    bf16*  cum   = (bf16*)(ws + 152 * MiB);
    float2* AH   = (float2*)(ws + 184 * MiB);

    // merged prep: casts + gate-W transpose + sp8
    cast_all<<<14369, 256, 0, stream>>>(x, Wxy, Wres, igw, agw, apar,
                                        xbf, wxyb, wresb, wT, sp8);

    // GEMM1: gemm_bt, single 2048-block launch (proven best at this grid size)
    gemm_bt<bf16><<<dim3(32, 64), 256, 0, stream>>>(xbf, wxyb, xy, 2048, 2048, 2048, 4096);

    // fused conv + gates + chunk summaries -> hloc (overlays xbf), cum, AH
    gate_kernel<<<dim3(NB_, 128), 256, 0, stream>>>(xy, cw, cb, wT, igb, agb, sp8,
                                                    hloc, cum, AH);

    // carry scan + elementwise passB -> g (overlays wT, dead by now)
    scan_carry<<<16, 256, 0, stream>>>(AH, cyb);
    scan_passB<<<8192, 256, 0, stream>>>(hloc, cum, cyb, xy, g);

    // GEMM2: gemm256, 256-block launch = 1 block/CU (proven best at this grid size)
    gemm256<float><<<dim3(8, 32), 512, 131072, stream>>>(g, wresb, out,
                                                         2048, 2048, 2048, 2048);
}